// Round 9
// baseline (53.551 us; speedup 1.0000x reference)
//
#include <hip/hip_runtime.h>
#include <math.h>

#define NT 100       // NUM_TOPICS
#define VOCAB 8192
#define TOPN 20
#define CAP 4096

// ---------------- per-topic top-20 via threshold filter (1024 thr) ----------------
// also zeroes *out (this node completes before the fused node starts)
__global__ __launch_bounds__(1024) void topk_kernel(
    const float* __restrict__ beta,
    int*   __restrict__ top_idx,   // [NT][TOPN]
    float* __restrict__ top_p,     // [NT][TOPN]
    float* __restrict__ rowstats,  // [NT][2] = {rowmax, full sumexp}
    float* __restrict__ out)
{
    const int k = blockIdx.x;
    const int t = threadIdx.x;
    if (k == 0 && t == 0) *out = 0.f;

    __shared__ float sred[16];
    __shared__ int   sredi[16];
    __shared__ int   s_base;
    __shared__ float cu[CAP];                // 16 KB candidate values
    __shared__ unsigned short ci[CAP];       // 8 KB candidate indices
    __shared__ float s_winv[TOPN];
    __shared__ int   s_wini[TOPN];
    __shared__ float s_ps;

    const float* row = beta + (size_t)k * VOCAB;

    float4 r0 = *reinterpret_cast<const float4*>(row + (size_t)t * 4);
    float4 r1 = *reinterpret_cast<const float4*>(row + (size_t)(1024 + t) * 4);

    float mx = fmaxf(fmaxf(fmaxf(r0.x, r0.y), fmaxf(r0.z, r0.w)),
                     fmaxf(fmaxf(r1.x, r1.y), fmaxf(r1.z, r1.w)));
#pragma unroll
    for (int off = 32; off >= 1; off >>= 1) mx = fmaxf(mx, __shfl_down(mx, off));
    if ((t & 63) == 0) sred[t >> 6] = mx;
    __syncthreads();
    float rowmax = sred[0];
#pragma unroll
    for (int w = 1; w < 16; ++w) rowmax = fmaxf(rowmax, sred[w]);
    __syncthreads();

    // threshold T with count(>=T) >= TOPN (1 iter typical for N(0,1))
    float T = rowmax - 2.0f;
    for (int guard = 0; guard < 64; ++guard) {
        int c = 0;
        c += (r0.x >= T) + (r0.y >= T) + (r0.z >= T) + (r0.w >= T);
        c += (r1.x >= T) + (r1.y >= T) + (r1.z >= T) + (r1.w >= T);
#pragma unroll
        for (int off = 32; off >= 1; off >>= 1) c += __shfl_down(c, off);
        if ((t & 63) == 0) sredi[t >> 6] = c;
        __syncthreads();
        int cnt = 0;
#pragma unroll
        for (int w = 0; w < 16; ++w) cnt += sredi[w];
        if (cnt >= TOPN) break;               // uniform decision
        T -= 0.5f;
        __syncthreads();
    }
    if (t == 0) s_base = 0;
    __syncthreads();

    // ballot-compact candidates from registers
#pragma unroll
    for (int i = 0; i < 2; ++i) {
        const float4 rr = (i == 0) ? r0 : r1;
#pragma unroll
        for (int e = 0; e < 4; ++e) {
            const float v = (&rr.x)[e];
            const int idx = (i * 1024 + t) * 4 + e;
            const bool pr = (v >= T);
            const unsigned long long mask = __ballot(pr);
            const int lane = t & 63;
            const int pre = __popcll(mask & ((1ull << lane) - 1ull));
            int base = 0;
            if (lane == 0) base = atomicAdd(&s_base, __popcll(mask));
            base = __shfl(base, 0);
            if (pr) {
                const int p = base + pre;
                if (p < CAP) { cu[p] = v; ci[p] = (unsigned short)idx; }
            }
        }
    }
    __syncthreads();
    const int ncand = min(s_base, CAP);

    // 20 extractions, single wave over candidate list
    if (t < 64) {
        for (int it = 0; it < TOPN; ++it) {
            float bv = -INFINITY; int bp = -1;
            for (int p = t; p < ncand; p += 64) {
                const float v = cu[p];
                if (v > bv) { bv = v; bp = p; }
            }
#pragma unroll
            for (int off = 32; off >= 1; off >>= 1) {
                const float ov = __shfl_down(bv, off);
                const int   op = __shfl_down(bp, off);
                if (ov > bv) { bv = ov; bp = op; }
            }
            bp = __shfl(bp, 0);
            bv = __shfl(bv, 0);
            if (t == 0) { s_winv[it] = bv; s_wini[it] = ci[bp]; }
            cu[bp] = -INFINITY;   // uniform same-addr write by the wave
        }
    }
    __syncthreads();

    if (t == 0) {
        float ps = 0.f;
#pragma unroll
        for (int j = 0; j < TOPN; ++j) ps += expf(s_winv[j] - rowmax);
        s_ps = ps;
    }
    __syncthreads();
    if (t < TOPN) {
        top_idx[k * TOPN + t] = s_wini[t];
        top_p[k * TOPN + t]   = expf(s_winv[t] - rowmax) / s_ps;
    }

    // full-row sumexp from registers
    float se = expf(r0.x - rowmax) + expf(r0.y - rowmax)
             + expf(r0.z - rowmax) + expf(r0.w - rowmax)
             + expf(r1.x - rowmax) + expf(r1.y - rowmax)
             + expf(r1.z - rowmax) + expf(r1.w - rowmax);
#pragma unroll
    for (int off = 32; off >= 1; off >>= 1) se += __shfl_down(se, off);
    if ((t & 63) == 0) sred[t >> 6] = se;
    __syncthreads();
    if (t == 0) {
        float s = 0.f;
#pragma unroll
        for (int w = 0; w < 16; ++w) s += sred[w];
        rowstats[2 * k + 0] = rowmax;
        rowstats[2 * k + 1] = s;
    }
}

// ---- fused gather + loss + per-topic finalize (100 blocks x 512 thr) ----
// one block per topic, full 8192-col row; per-topic scalar atomicAdd'ed to out
__global__ __launch_bounds__(512) void fused_kernel(
    const float* __restrict__ beta,
    const float* __restrict__ W,
    const int*   __restrict__ top_idx,
    const float* __restrict__ top_p,
    const float* __restrict__ rowstats,
    const int*   __restrict__ epoch,
    float* __restrict__ out)
{
    const int k = blockIdx.x;
    const int t = threadIdx.x;

    __shared__ int   cnt[VOCAB];             // 32 KB full-row histogram
    __shared__ int   sIdx[TOPN];
    __shared__ float sP[TOPN];
    __shared__ float sA[8], sB[8], sC[8], sD[8], sE[8], sF[8];

    if (t < TOPN) { sIdx[t] = top_idx[k * TOPN + t]; sP[t] = top_p[k * TOPN + t]; }
#pragma unroll
    for (int i = 0; i < VOCAB / 512; ++i) cnt[i * 512 + t] = 0;
    __syncthreads();

    // full-row histogram over all topics' top-20 (2000 entries), minus own topic
#pragma unroll 4
    for (int e = t; e < NT * TOPN; e += 512) atomicAdd(&cnt[top_idx[e]], 1);
    if (t < TOPN) atomicSub(&cnt[sIdx[t]], 1);

    int   idx_r[TOPN];
    float p_r[TOPN];
#pragma unroll
    for (int j = 0; j < TOPN; ++j) { idx_r[j] = sIdx[j]; p_r[j] = sP[j]; }

    const float rmax = rowstats[2 * k + 0];
    const float rinv = 1.0f / rowstats[2 * k + 1];

    __syncthreads();                         // cnt final

    float mn = INFINITY, mxv = -INFINITY;
    float Apos = 0.f, Bpos = 0.f, Aneg = 0.f, Bneg = 0.f;

#pragma unroll
    for (int s = 0; s < 4; ++s) {            // 4 segments x 512 thr x float4
        const int col = s * 2048 + t * 4;

        float4 m = make_float4(0.f, 0.f, 0.f, 0.f);
#pragma unroll
        for (int j = 0; j < TOPN; ++j) {
            const float4 w = *reinterpret_cast<const float4*>(W + (size_t)idx_r[j] * VOCAB + col);
            const float pj = p_r[j];
            m.x += pj * w.x; m.y += pj * w.y; m.z += pj * w.z; m.w += pj * w.w;
        }
        mn  = fminf(mn,  fminf(fminf(m.x, m.y), fminf(m.z, m.w)));
        mxv = fmaxf(mxv, fmaxf(fmaxf(m.x, m.y), fmaxf(m.z, m.w)));

        const float4 bv = *reinterpret_cast<const float4*>(beta + (size_t)k * VOCAB + col);
        float4 w4;
        w4.x = expf(bv.x - rmax) * rinv;  w4.x = 100.f * w4.x * w4.x;
        w4.y = expf(bv.y - rmax) * rinv;  w4.y = 100.f * w4.y * w4.y;
        w4.z = expf(bv.z - rmax) * rinv;  w4.z = 100.f * w4.z * w4.z;
        w4.w = expf(bv.w - rmax) * rinv;  w4.w = 100.f * w4.w * w4.w;

        const int4 c4 = *reinterpret_cast<const int4*>(cnt + col);
        if (c4.x > 0) { Apos += w4.x; Bpos += w4.x * m.x; } else { Aneg += w4.x; Bneg += w4.x * m.x; }
        if (c4.y > 0) { Apos += w4.y; Bpos += w4.y * m.y; } else { Aneg += w4.y; Bneg += w4.y * m.y; }
        if (c4.z > 0) { Apos += w4.z; Bpos += w4.z * m.z; } else { Aneg += w4.z; Bneg += w4.z * m.z; }
        if (c4.w > 0) { Apos += w4.w; Bpos += w4.w * m.w; } else { Aneg += w4.w; Bneg += w4.w * m.w; }
    }

#pragma unroll
    for (int off = 32; off >= 1; off >>= 1) {
        mn   = fminf(mn,  __shfl_down(mn,  off));
        mxv  = fmaxf(mxv, __shfl_down(mxv, off));
        Apos += __shfl_down(Apos, off);
        Bpos += __shfl_down(Bpos, off);
        Aneg += __shfl_down(Aneg, off);
        Bneg += __shfl_down(Bneg, off);
    }
    if ((t & 63) == 0) {
        const int w = t >> 6;
        sA[w] = mn; sB[w] = mxv; sC[w] = Apos; sD[w] = Bpos; sE[w] = Aneg; sF[w] = Bneg;
    }
    __syncthreads();
    if (t == 0) {
        float a = sA[0], b = sB[0], Ap = 0.f, Bp = 0.f, An = 0.f, Bn = 0.f;
#pragma unroll
        for (int w = 0; w < 8; ++w) {
            a  = fminf(a, sA[w]);
            b  = fmaxf(b, sB[w]);
            Ap += sC[w]; Bp += sD[w]; An += sE[w]; Bn += sF[w];
        }
        const float inv = 1.0f / (b - a);
        const float pos = Ap - inv * (Bp - a * Ap);   // sum w*(1-(M-mn)*inv)
        const float neg = An - inv * (Bn - a * An);
        const int e = *epoch;
        const float la = (e < 100) ? (float)e : 100.0f;   // lambda_a_delta = 1
        atomicAdd(out, la * (pos * 0.7f + neg * 0.3f) * 2.0f);
    }
}

extern "C" void kernel_launch(void* const* d_in, const int* in_sizes, int n_in,
                              void* d_out, int out_size, void* d_ws, size_t ws_size,
                              hipStream_t stream)
{
    (void)in_sizes; (void)n_in; (void)out_size; (void)ws_size;
    const float* beta  = (const float*)d_in[0];
    const float* W     = (const float*)d_in[1];
    const int*   epoch = (const int*)d_in[2];
    float* out = (float*)d_out;

    char* ws = (char*)d_ws;
    int*   top_idx  = (int*)ws;    ws += NT * TOPN * sizeof(int);
    float* top_p    = (float*)ws;  ws += NT * TOPN * sizeof(float);
    float* rowstats = (float*)ws;  ws += NT * 2 * sizeof(float);

    topk_kernel<<<NT, 1024, 0, stream>>>(beta, top_idx, top_p, rowstats, out);
    fused_kernel<<<NT, 512, 0, stream>>>(beta, W, top_idx, top_p, rowstats, epoch, out);
}